// Round 4
// baseline (306.597 us; speedup 1.0000x reference)
//
#include <hip/hip_runtime.h>
#include <math.h>

constexpr int B_    = 32;
constexpr int In_   = 2048;
constexpr int Din_  = 8;
constexpr int N_    = 64;
constexpr int Dout_ = 16;
constexpr int C_    = 32;
constexpr int ICP   = 64;     // In_/C_
constexpr int GRID  = 512;    // 2 blocks/CU needed; LDS caps at 5/CU -> 2.5x margin
constexpr float EPS = 1e-7f;

// Single shared-memory block reused by every phase (30.25 KB).
struct Smem {
    float Us[N_][8];        // 2 KB
    float xs[ICP][8];       // 2 KB
    float lg[ICP][68];      // 17 KB (b128-aligned rows)
    float ps[4][ICP];       // 1 KB
    float inv_s[ICP];       // 256 B
    float ys[4][N_][8];     // 8 KB
};

// ---------------------------------------------------------------------------
// Lightweight grid barrier: agent-scope atomics + short-sleep spin.
// cnt/flag pre-zeroed by a hipMemsetAsync before the kernel. ~1-3 us each
// (vs ~60 us for cg::grid.sync measured in R3).
// ---------------------------------------------------------------------------
__device__ __forceinline__ void gbar(unsigned* cnt, unsigned* flag, unsigned nb)
{
    __syncthreads();
    if (threadIdx.x == 0) {
        __threadfence();   // make this block's prior global writes visible
        const unsigned old = __hip_atomic_fetch_add(
            cnt, 1u, __ATOMIC_ACQ_REL, __HIP_MEMORY_SCOPE_AGENT);
        if (old == nb - 1u) {
            __hip_atomic_store(flag, 1u, __ATOMIC_RELEASE, __HIP_MEMORY_SCOPE_AGENT);
        } else {
            while (__hip_atomic_load(flag, __ATOMIC_ACQUIRE,
                                     __HIP_MEMORY_SCOPE_AGENT) == 0u)
                __builtin_amdgcn_s_sleep(8);
        }
        __threadfence();   // acquire: invalidate caches before post-barrier reads
    }
    __syncthreads();
}

// ---------------------------------------------------------------------------
// Phase 0: v0 = squash(sum_c W[n,c,:,:].xbar[c,:] + bias). Logical blocks
// 0..255, block = (b, j): covers n in [8j, 8j+8).
// ---------------------------------------------------------------------------
__device__ __forceinline__ void v0_body(
    Smem* sm, int blk,
    const float* __restrict__ x, const float* __restrict__ W,
    const float* __restrict__ bias, float* __restrict__ v0)
{
    const int b = blk >> 3, j = blk & 7;
    const int t = threadIdx.x;
    float (*xbar)[8] = (float(*)[8])(&sm->Us[0][0]);   // 32x8 fits in Us

    {
        const int c = t >> 3, k = t & 7;
        const float* xp = x + (size_t)b * In_ * Din_ + (size_t)c * ICP * Din_ + k;
        float acc = 0.f;
        #pragma unroll 8
        for (int i = 0; i < ICP; ++i) acc += xp[i * Din_];
        xbar[c][k] = acc * (1.f / 64.f);
    }
    __syncthreads();

    {
        const int nl = t >> 5, lane32 = t & 31;
        const int d = lane32 >> 1, h = lane32 & 1;
        const int n = j * 8 + nl;

        float a = 0.f;
        #pragma unroll
        for (int cc = 0; cc < 16; ++cc) {
            const int c2 = cc * 2 + h;
            const float4* wp = (const float4*)(W + (((size_t)n * C_ + c2) * Dout_ + d) * Din_);
            const float4 w0 = wp[0], w1 = wp[1];
            a += w0.x * xbar[c2][0] + w0.y * xbar[c2][1] + w0.z * xbar[c2][2] + w0.w * xbar[c2][3]
               + w1.x * xbar[c2][4] + w1.y * xbar[c2][5] + w1.z * xbar[c2][6] + w1.w * xbar[c2][7];
        }
        a += __shfl_xor(a, 1);
        a += bias[n * Dout_ + d];

        float sn = a * a;
        sn += __shfl_xor(sn, 2);
        sn += __shfl_xor(sn, 4);
        sn += __shfl_xor(sn, 8);
        sn += __shfl_xor(sn, 16);
        const float sc = sn / (1.f + sn) / sqrtf(sn + EPS);
        if (h == 0) v0[(size_t)b * 1024 + n * Dout_ + d] = a * sc;
    }
}

// ---------------------------------------------------------------------------
// Routing iteration for one (b,c) tile. vv = this thread's v[b][n4][4q4..4q4+4)
// held in registers (no global round-trip for the accumulated v).
// ---------------------------------------------------------------------------
__device__ __forceinline__ void route_body(
    Smem* sm, int b, int c, float4 vv,
    const float* __restrict__ x, const float* __restrict__ W,
    float* __restrict__ s_out)
{
    const int t = threadIdx.x;
    const int w = t >> 6, l = t & 63;
    const int n4 = t >> 2, q4 = t & 3;

    // ---- U stage
    {
        const float vd[4] = {vv.x, vv.y, vv.z, vv.w};
        float pU[8] = {0, 0, 0, 0, 0, 0, 0, 0};
        #pragma unroll
        for (int dd = 0; dd < 4; ++dd) {
            const int d = q4 * 4 + dd;
            const float4* wp = (const float4*)(W + (((size_t)n4 * 32 + c) * 16 + d) * 8);
            const float4 w0 = wp[0], w1 = wp[1];
            const float v_ = vd[dd];
            pU[0] += v_ * w0.x; pU[1] += v_ * w0.y; pU[2] += v_ * w0.z; pU[3] += v_ * w0.w;
            pU[4] += v_ * w1.x; pU[5] += v_ * w1.y; pU[6] += v_ * w1.z; pU[7] += v_ * w1.w;
        }
        #pragma unroll
        for (int k = 0; k < 8; ++k) {
            pU[k] += __shfl_xor(pU[k], 1);
            pU[k] += __shfl_xor(pU[k], 2);
        }
        float2 u2; u2.x = pU[2 * q4]; u2.y = pU[2 * q4 + 1];
        *(float2*)&sm->Us[n4][2 * q4] = u2;
    }

    // ---- x fragment for lane's capsule i = l; wave 0 mirrors to LDS
    float xr[8];
    {
        const float4* xp = (const float4*)(x + ((size_t)b * In_ + c * ICP + l) * 8);
        const float4 x0 = xp[0], x1 = xp[1];
        xr[0] = x0.x; xr[1] = x0.y; xr[2] = x0.z; xr[3] = x0.w;
        xr[4] = x1.x; xr[5] = x1.y; xr[6] = x1.z; xr[7] = x1.w;
        if (w == 0) { *(float4*)&sm->xs[l][0] = x0; *(float4*)&sm->xs[l][4] = x1; }
    }
    __syncthreads();

    // ---- logits+exp: wave w covers n in [16w,16w+16); lane = i
    {
        float e[16];
        float ssum = 0.f;
        #pragma unroll
        for (int nn = 0; nn < 16; ++nn) {
            const int n = w * 16 + nn;
            const float4 u0 = *(const float4*)&sm->Us[n][0];
            const float4 u1 = *(const float4*)&sm->Us[n][4];
            const float a = u0.x * xr[0] + u0.y * xr[1] + u0.z * xr[2] + u0.w * xr[3]
                          + u1.x * xr[4] + u1.y * xr[5] + u1.z * xr[6] + u1.w * xr[7];
            const float ee = __expf(a);    // logits bounded (validated earlier)
            e[nn] = ee; ssum += ee;
        }
        #pragma unroll
        for (int qq = 0; qq < 4; ++qq) {
            float4 o;
            o.x = e[qq * 4 + 0]; o.y = e[qq * 4 + 1]; o.z = e[qq * 4 + 2]; o.w = e[qq * 4 + 3];
            *(float4*)&sm->lg[l][w * 16 + qq * 4] = o;
        }
        sm->ps[w][l] = ssum;
    }
    __syncthreads();

    if (t < 64) sm->inv_s[t] = 1.f / (sm->ps[0][t] + sm->ps[1][t] + sm->ps[2][t] + sm->ps[3][t]);
    __syncthreads();

    // ---- y stage
    {
        const int nq = l >> 2, kq = l & 3;
        float y[8] = {0, 0, 0, 0, 0, 0, 0, 0};
        #pragma unroll
        for (int ii = 0; ii < 16; ++ii) {
            const int i = w * 16 + ii;
            const float4 cw = *(const float4*)&sm->lg[i][nq * 4];
            const float iv = sm->inv_s[i];
            const float2 x2 = *(const float2*)&sm->xs[i][kq * 2];
            const float c0 = cw.x * iv, c1 = cw.y * iv, c2 = cw.z * iv, c3 = cw.w * iv;
            y[0] += c0 * x2.x; y[1] += c0 * x2.y;
            y[2] += c1 * x2.x; y[3] += c1 * x2.y;
            y[4] += c2 * x2.x; y[5] += c2 * x2.y;
            y[6] += c3 * x2.x; y[7] += c3 * x2.y;
        }
        #pragma unroll
        for (int jj = 0; jj < 4; ++jj) {
            float2 o; o.x = y[2 * jj]; o.y = y[2 * jj + 1];
            *(float2*)&sm->ys[w][nq * 4 + jj][kq * 2] = o;
        }
    }
    __syncthreads();

    // ---- s stage
    {
        float yn[8];
        #pragma unroll
        for (int k = 0; k < 8; ++k)
            yn[k] = sm->ys[0][n4][k] + sm->ys[1][n4][k] + sm->ys[2][n4][k] + sm->ys[3][n4][k];
        float4 o;
        float* op = (float*)&o;
        #pragma unroll
        for (int dd = 0; dd < 4; ++dd) {
            const int d = q4 * 4 + dd;
            const float4* wp = (const float4*)(W + (((size_t)n4 * 32 + c) * 16 + d) * 8);
            const float4 w0 = wp[0], w1 = wp[1];
            op[dd] = w0.x * yn[0] + w0.y * yn[1] + w0.z * yn[2] + w0.w * yn[3]
                   + w1.x * yn[4] + w1.y * yn[5] + w1.z * yn[6] + w1.w * yn[7];
        }
        *(float4*)(s_out + (((size_t)b * 32 + c) * 64 + n4) * 16 + q4 * 4) = o;
    }
}

// ---------------------------------------------------------------------------
// In-register vsum prologue for route2: thread (n4,q4) computes
// vsum[b][n4][4q4..+4) = v0 + squash(sum_c s1[b][c][n4][:] + bias) directly
// in the layout route_body's U stage consumes. Replaces the reduce1 kernel
// and its barrier + global round-trip.
// ---------------------------------------------------------------------------
__device__ __forceinline__ float4 vsum_tile(
    int b, const float* __restrict__ s1, const float* __restrict__ bias,
    const float* __restrict__ v0buf)
{
    const int t = threadIdx.x, n4 = t >> 2, q4 = t & 3;
    float a0 = 0.f, a1 = 0.f, a2 = 0.f, a3 = 0.f;
    const float* sp = s1 + ((size_t)b * 32 * 64 + n4) * 16 + q4 * 4;
    #pragma unroll 8
    for (int c = 0; c < 32; ++c) {
        const float4 sv = *(const float4*)(sp + (size_t)c * 1024);
        a0 += sv.x; a1 += sv.y; a2 += sv.z; a3 += sv.w;
    }
    const float4 bi = *(const float4*)(bias + n4 * 16 + q4 * 4);
    a0 += bi.x; a1 += bi.y; a2 += bi.z; a3 += bi.w;

    float sn = a0 * a0 + a1 * a1 + a2 * a2 + a3 * a3;
    sn += __shfl_xor(sn, 1);
    sn += __shfl_xor(sn, 2);          // full sum over the 16 d (q4 lanes)
    const float sc = sn / (1.f + sn) / sqrtf(sn + EPS);

    const float4 v0v = *(const float4*)(v0buf + (size_t)b * 1024 + n4 * 16 + q4 * 4);
    float4 r;
    r.x = v0v.x + a0 * sc; r.y = v0v.y + a1 * sc;
    r.z = v0v.z + a2 * sc; r.w = v0v.w + a3 * sc;
    return r;
}

// ---------------------------------------------------------------------------
// Final reduce s2 over c + bias + squash -> out. Logical blocks 0..255.
// ---------------------------------------------------------------------------
__device__ __forceinline__ void reduce_body(
    int blk, const float* __restrict__ s_src, const float* __restrict__ bias,
    float* __restrict__ dst)
{
    const int b = blk >> 3, j = blk & 7;
    const int t = threadIdx.x;
    const int nl = t >> 5, lane32 = t & 31;
    const int d = lane32 >> 1, h = lane32 & 1;
    const int n = j * 8 + nl;

    float a = 0.f;
    #pragma unroll
    for (int cc = 0; cc < 16; ++cc) {
        const int c2 = cc * 2 + h;
        a += s_src[(((size_t)b * 32 + c2) * 64 + n) * 16 + d];
    }
    a += __shfl_xor(a, 1);
    a += bias[n * Dout_ + d];

    float sn = a * a;
    sn += __shfl_xor(sn, 2);
    sn += __shfl_xor(sn, 4);
    sn += __shfl_xor(sn, 8);
    sn += __shfl_xor(sn, 16);
    const float sc = sn / (1.f + sn) / sqrtf(sn + EPS);
    if (h == 0) dst[(size_t)b * 1024 + n * Dout_ + d] = a * sc;
}

// ---------------------------------------------------------------------------
// Persistent single kernel, PLAIN launch (graph-capturable). 512 blocks x
// 256 threads; all co-resident (LDS 30.25KB -> 5 blocks/CU capacity, need 2).
// 3 custom grid barriers. Each block handles 2 (b,c) route tiles per iter.
// ---------------------------------------------------------------------------
__global__ __launch_bounds__(256, 2) void caps_persist(
    const float* __restrict__ x, const float* __restrict__ W,
    const float* __restrict__ bias, float* __restrict__ out,
    float* __restrict__ s1, float* __restrict__ s2,
    float* __restrict__ v0buf, unsigned* __restrict__ bar)
{
    __shared__ Smem sm;
    const int blk = blockIdx.x;
    const int n4 = threadIdx.x >> 2, q4 = threadIdx.x & 3;

    // P0: v0
    if (blk < 256) v0_body(&sm, blk, x, W, bias, v0buf);
    gbar(&bar[0], &bar[1], GRID);

    // P1: route1 (tiles blk and blk+512)
    {
        int b = blk >> 5, c = blk & 31;
        float4 vv = *(const float4*)(v0buf + ((size_t)b * 64 + n4) * 16 + q4 * 4);
        route_body(&sm, b, c, vv, x, W, s1);
        __syncthreads();
        const int blk2 = blk + GRID;
        b = blk2 >> 5; c = blk2 & 31;
        vv = *(const float4*)(v0buf + ((size_t)b * 64 + n4) * 16 + q4 * 4);
        route_body(&sm, b, c, vv, x, W, s1);
    }
    gbar(&bar[32], &bar[33], GRID);

    // P2: in-register vsum + route2
    {
        int b = blk >> 5, c = blk & 31;
        float4 vv = vsum_tile(b, s1, bias, v0buf);
        route_body(&sm, b, c, vv, x, W, s2);
        __syncthreads();
        const int blk2 = blk + GRID;
        b = blk2 >> 5; c = blk2 & 31;
        vv = vsum_tile(b, s1, bias, v0buf);
        route_body(&sm, b, c, vv, x, W, s2);
    }
    gbar(&bar[64], &bar[65], GRID);

    // P3: final reduce -> out
    if (blk < 256) reduce_body(blk, s2, bias, out);
}

extern "C" void kernel_launch(void* const* d_in, const int* in_sizes, int n_in,
                              void* d_out, int out_size, void* d_ws, size_t ws_size,
                              hipStream_t stream) {
    const float* x    = (const float*)d_in[0];   // [B, In, Din]
    const float* W    = (const float*)d_in[1];   // [N, C, Dout, Din]
    const float* bias = (const float*)d_in[2];   // [N, Dout]
    float* out = (float*)d_out;                  // [B, N, Dout]

    float* ws   = (float*)d_ws;
    float* s1   = ws;                                   // 1,048,576 f
    float* s2   = s1 + (size_t)B_ * C_ * N_ * Dout_;    // 1,048,576 f
    float* v0b  = s2 + (size_t)B_ * C_ * N_ * Dout_;    // 32,768 f
    unsigned* bar = (unsigned*)(v0b + (size_t)B_ * N_ * Dout_);  // 96 u32, 128B-aligned

    // Zero the barrier state (workspace is poisoned between iterations).
    hipMemsetAsync(bar, 0, 96 * sizeof(unsigned), stream);

    caps_persist<<<GRID, 256, 0, stream>>>(x, W, bias, out, s1, s2, v0b, bar);
}

// Round 5
// 163.851 us; speedup vs baseline: 1.8712x; 1.8712x over previous
//
#include <hip/hip_runtime.h>
#include <math.h>

constexpr int B_    = 32;
constexpr int In_   = 2048;
constexpr int Din_  = 8;
constexpr int N_    = 64;
constexpr int Dout_ = 16;
constexpr int C_    = 32;
constexpr int ICP   = 64;     // In_/C_
constexpr int GRID  = 256;    // 1 block/CU needed; LDS allows 5/CU -> all resident
constexpr float EPS = 1e-7f;

// Single shared-memory block reused by every phase (30.25 KB).
struct Smem {
    float Us[N_][8];        // 2 KB
    float xs[ICP][8];       // 2 KB
    float lg[ICP][68];      // 17 KB (b128-aligned rows)
    float ps[4][ICP];       // 1 KB
    float inv_s[ICP];       // 256 B
    float ys[4][N_][8];     // 8 KB
};

// ---------------------------------------------------------------------------
// Per-b 8-participant barrier. Each b has its own 128B line (no cross-b
// contention; R3/R4 showed 512-way same-line barriers cost ~75us each).
// cnt pre-zeroed by hipMemsetAsync. Poll cnt directly (no flag needed at 8).
// ---------------------------------------------------------------------------
__device__ __forceinline__ void gbar8(unsigned* cnt)
{
    __syncthreads();
    if (threadIdx.x == 0) {
        __threadfence();   // release: drain this block's global writes
        __hip_atomic_fetch_add(cnt, 1u, __ATOMIC_ACQ_REL, __HIP_MEMORY_SCOPE_AGENT);
        while (__hip_atomic_load(cnt, __ATOMIC_ACQUIRE,
                                 __HIP_MEMORY_SCOPE_AGENT) < 8u)
            __builtin_amdgcn_s_sleep(1);
        __threadfence();   // acquire: invalidate before reading peers' data
    }
    __syncthreads();
}

// ---------------------------------------------------------------------------
// Phase 0: v0 slice for 8 n. bid=(b,g) maps exactly onto the old (b,j).
// ---------------------------------------------------------------------------
__device__ __forceinline__ void v0_body(
    Smem* sm, int blk,
    const float* __restrict__ x, const float* __restrict__ W,
    const float* __restrict__ bias, float* __restrict__ v0)
{
    const int b = blk >> 3, j = blk & 7;
    const int t = threadIdx.x;
    float (*xbar)[8] = (float(*)[8])(&sm->Us[0][0]);   // 32x8 fits in Us

    {
        const int c = t >> 3, k = t & 7;
        const float* xp = x + (size_t)b * In_ * Din_ + (size_t)c * ICP * Din_ + k;
        float acc = 0.f;
        #pragma unroll 8
        for (int i = 0; i < ICP; ++i) acc += xp[i * Din_];
        xbar[c][k] = acc * (1.f / 64.f);
    }
    __syncthreads();

    {
        const int nl = t >> 5, lane32 = t & 31;
        const int d = lane32 >> 1, h = lane32 & 1;
        const int n = j * 8 + nl;

        float a = 0.f;
        #pragma unroll
        for (int cc = 0; cc < 16; ++cc) {
            const int c2 = cc * 2 + h;
            const float4* wp = (const float4*)(W + (((size_t)n * C_ + c2) * Dout_ + d) * Din_);
            const float4 w0 = wp[0], w1 = wp[1];
            a += w0.x * xbar[c2][0] + w0.y * xbar[c2][1] + w0.z * xbar[c2][2] + w0.w * xbar[c2][3]
               + w1.x * xbar[c2][4] + w1.y * xbar[c2][5] + w1.z * xbar[c2][6] + w1.w * xbar[c2][7];
        }
        a += __shfl_xor(a, 1);
        a += bias[n * Dout_ + d];

        float sn = a * a;
        sn += __shfl_xor(sn, 2);
        sn += __shfl_xor(sn, 4);
        sn += __shfl_xor(sn, 8);
        sn += __shfl_xor(sn, 16);
        const float sc = sn / (1.f + sn) / sqrtf(sn + EPS);
        if (h == 0) v0[(size_t)b * 1024 + n * Dout_ + d] = a * sc;
    }
    __syncthreads();   // xbar (aliasing Us) dead before route reuses Us
}

// ---------------------------------------------------------------------------
// Routing iteration for one (b,c) tile. vv = this thread's v[b][n4][4q4..+4)
// in registers. s-result ACCUMULATES into *acc (thread (n4,q4) owns
// s[n4][4q4..+4) — consistent across c calls).
// ---------------------------------------------------------------------------
__device__ __forceinline__ void route_body(
    Smem* sm, int b, int c, float4 vv,
    const float* __restrict__ x, const float* __restrict__ W,
    float4* acc)
{
    const int t = threadIdx.x;
    const int w = t >> 6, l = t & 63;
    const int n4 = t >> 2, q4 = t & 3;

    // ---- U stage
    {
        const float vd[4] = {vv.x, vv.y, vv.z, vv.w};
        float pU[8] = {0, 0, 0, 0, 0, 0, 0, 0};
        #pragma unroll
        for (int dd = 0; dd < 4; ++dd) {
            const int d = q4 * 4 + dd;
            const float4* wp = (const float4*)(W + (((size_t)n4 * 32 + c) * 16 + d) * 8);
            const float4 w0 = wp[0], w1 = wp[1];
            const float v_ = vd[dd];
            pU[0] += v_ * w0.x; pU[1] += v_ * w0.y; pU[2] += v_ * w0.z; pU[3] += v_ * w0.w;
            pU[4] += v_ * w1.x; pU[5] += v_ * w1.y; pU[6] += v_ * w1.z; pU[7] += v_ * w1.w;
        }
        #pragma unroll
        for (int k = 0; k < 8; ++k) {
            pU[k] += __shfl_xor(pU[k], 1);
            pU[k] += __shfl_xor(pU[k], 2);
        }
        float2 u2; u2.x = pU[2 * q4]; u2.y = pU[2 * q4 + 1];
        *(float2*)&sm->Us[n4][2 * q4] = u2;
    }

    // ---- x fragment for lane's capsule i = l; wave 0 mirrors to LDS
    float xr[8];
    {
        const float4* xp = (const float4*)(x + ((size_t)b * In_ + c * ICP + l) * 8);
        const float4 x0 = xp[0], x1 = xp[1];
        xr[0] = x0.x; xr[1] = x0.y; xr[2] = x0.z; xr[3] = x0.w;
        xr[4] = x1.x; xr[5] = x1.y; xr[6] = x1.z; xr[7] = x1.w;
        if (w == 0) { *(float4*)&sm->xs[l][0] = x0; *(float4*)&sm->xs[l][4] = x1; }
    }
    __syncthreads();

    // ---- logits+exp: wave w covers n in [16w,16w+16); lane = i
    {
        float e[16];
        float ssum = 0.f;
        #pragma unroll
        for (int nn = 0; nn < 16; ++nn) {
            const int n = w * 16 + nn;
            const float4 u0 = *(const float4*)&sm->Us[n][0];
            const float4 u1 = *(const float4*)&sm->Us[n][4];
            const float a = u0.x * xr[0] + u0.y * xr[1] + u0.z * xr[2] + u0.w * xr[3]
                          + u1.x * xr[4] + u1.y * xr[5] + u1.z * xr[6] + u1.w * xr[7];
            const float ee = __expf(a);    // logits bounded (validated earlier)
            e[nn] = ee; ssum += ee;
        }
        #pragma unroll
        for (int qq = 0; qq < 4; ++qq) {
            float4 o;
            o.x = e[qq * 4 + 0]; o.y = e[qq * 4 + 1]; o.z = e[qq * 4 + 2]; o.w = e[qq * 4 + 3];
            *(float4*)&sm->lg[l][w * 16 + qq * 4] = o;
        }
        sm->ps[w][l] = ssum;
    }
    __syncthreads();

    if (t < 64) sm->inv_s[t] = 1.f / (sm->ps[0][t] + sm->ps[1][t] + sm->ps[2][t] + sm->ps[3][t]);
    __syncthreads();

    // ---- y stage
    {
        const int nq = l >> 2, kq = l & 3;
        float y[8] = {0, 0, 0, 0, 0, 0, 0, 0};
        #pragma unroll
        for (int ii = 0; ii < 16; ++ii) {
            const int i = w * 16 + ii;
            const float4 cw = *(const float4*)&sm->lg[i][nq * 4];
            const float iv = sm->inv_s[i];
            const float2 x2 = *(const float2*)&sm->xs[i][kq * 2];
            const float c0 = cw.x * iv, c1 = cw.y * iv, c2 = cw.z * iv, c3 = cw.w * iv;
            y[0] += c0 * x2.x; y[1] += c0 * x2.y;
            y[2] += c1 * x2.x; y[3] += c1 * x2.y;
            y[4] += c2 * x2.x; y[5] += c2 * x2.y;
            y[6] += c3 * x2.x; y[7] += c3 * x2.y;
        }
        #pragma unroll
        for (int jj = 0; jj < 4; ++jj) {
            float2 o; o.x = y[2 * jj]; o.y = y[2 * jj + 1];
            *(float2*)&sm->ys[w][nq * 4 + jj][kq * 2] = o;
        }
    }
    __syncthreads();

    // ---- s stage: accumulate this c's contribution into acc
    {
        float yn[8];
        #pragma unroll
        for (int k = 0; k < 8; ++k)
            yn[k] = sm->ys[0][n4][k] + sm->ys[1][n4][k] + sm->ys[2][n4][k] + sm->ys[3][n4][k];
        float o[4];
        #pragma unroll
        for (int dd = 0; dd < 4; ++dd) {
            const int d = q4 * 4 + dd;
            const float4* wp = (const float4*)(W + (((size_t)n4 * 32 + c) * 16 + d) * 8);
            const float4 w0 = wp[0], w1 = wp[1];
            o[dd] = w0.x * yn[0] + w0.y * yn[1] + w0.z * yn[2] + w0.w * yn[3]
                  + w1.x * yn[4] + w1.y * yn[5] + w1.z * yn[6] + w1.w * yn[7];
        }
        acc->x += o[0]; acc->y += o[1]; acc->z += o[2]; acc->w += o[3];
    }
    __syncthreads();   // ys dead before next call's stages reuse LDS
}

// ---------------------------------------------------------------------------
// Sum the 8 per-g partials of batch b + bias, squash. Thread (n4,q4) returns
// the squashed value for (n4, 4q4..+4). Quad shfl gives the full-d norm.
// ---------------------------------------------------------------------------
__device__ __forceinline__ float4 squash_from_parts(
    int b, const float* __restrict__ sp, const float* __restrict__ bias)
{
    const int t = threadIdx.x, n4 = t >> 2, q4 = t & 3;
    float a0 = 0.f, a1 = 0.f, a2 = 0.f, a3 = 0.f;
    const float* p = sp + (size_t)b * 8 * 1024 + n4 * 16 + q4 * 4;
    #pragma unroll
    for (int g2 = 0; g2 < 8; ++g2) {
        const float4 sv = *(const float4*)(p + (size_t)g2 * 1024);
        a0 += sv.x; a1 += sv.y; a2 += sv.z; a3 += sv.w;
    }
    const float4 bi = *(const float4*)(bias + n4 * 16 + q4 * 4);
    a0 += bi.x; a1 += bi.y; a2 += bi.z; a3 += bi.w;

    float sn = a0 * a0 + a1 * a1 + a2 * a2 + a3 * a3;
    sn += __shfl_xor(sn, 1);
    sn += __shfl_xor(sn, 2);          // full sum over the 16 d (quad lanes)
    const float sc = sn / (1.f + sn) / sqrtf(sn + EPS);
    float4 r; r.x = a0 * sc; r.y = a1 * sc; r.z = a2 * sc; r.w = a3 * sc;
    return r;
}

// ---------------------------------------------------------------------------
// Persistent kernel, plain launch. 256 blocks = (b in [0,32)) x (g in [0,8)).
// Block (b,g) handles c in [4g, 4g+4). All cross-block sync is per-b 8-way.
// ---------------------------------------------------------------------------
__global__ __launch_bounds__(256, 2) void caps_persist(
    const float* __restrict__ x, const float* __restrict__ W,
    const float* __restrict__ bias, float* __restrict__ out,
    float* __restrict__ spart1, float* __restrict__ spart2,
    float* __restrict__ v0buf, unsigned* __restrict__ bar)
{
    __shared__ Smem sm;
    const int bid = blockIdx.x;
    const int b = bid >> 3, g = bid & 7;
    const int n4 = threadIdx.x >> 2, q4 = threadIdx.x & 3;
    unsigned* bline = bar + (size_t)b * 32;   // one 128B line per b

    // P0: v0 (this block's 8-n slice)
    v0_body(&sm, bid, x, W, bias, v0buf);
    gbar8(&bline[0]);

    // P1: route1 over this block's 4 c's; store partial s1
    {
        const float4 vv = *(const float4*)(v0buf + (size_t)b * 1024 + n4 * 16 + q4 * 4);
        float4 acc = {0.f, 0.f, 0.f, 0.f};
        #pragma unroll
        for (int cc = 0; cc < 4; ++cc)
            route_body(&sm, b, g * 4 + cc, vv, x, W, &acc);
        *(float4*)(spart1 + (size_t)bid * 1024 + n4 * 16 + q4 * 4) = acc;
    }
    gbar8(&bline[8]);

    // P2: vsum = v0 + squash(sum s1 + bias) in registers; route2; partial s2
    {
        const float4 sq = squash_from_parts(b, spart1, bias);
        const float4 v0v = *(const float4*)(v0buf + (size_t)b * 1024 + n4 * 16 + q4 * 4);
        float4 vv; vv.x = v0v.x + sq.x; vv.y = v0v.y + sq.y;
        vv.z = v0v.z + sq.z; vv.w = v0v.w + sq.w;
        float4 acc = {0.f, 0.f, 0.f, 0.f};
        #pragma unroll
        for (int cc = 0; cc < 4; ++cc)
            route_body(&sm, b, g * 4 + cc, vv, x, W, &acc);
        *(float4*)(spart2 + (size_t)bid * 1024 + n4 * 16 + q4 * 4) = acc;
    }

    // P3: arrive-only for g!=0; g==0 waits then reduces -> out
    __syncthreads();
    if (threadIdx.x == 0) {
        __threadfence();
        __hip_atomic_fetch_add(&bline[16], 1u, __ATOMIC_ACQ_REL,
                               __HIP_MEMORY_SCOPE_AGENT);
    }
    if (g != 0) return;
    if (threadIdx.x == 0) {
        while (__hip_atomic_load(&bline[16], __ATOMIC_ACQUIRE,
                                 __HIP_MEMORY_SCOPE_AGENT) < 8u)
            __builtin_amdgcn_s_sleep(1);
        __threadfence();
    }
    __syncthreads();
    {
        const float4 r = squash_from_parts(b, spart2, bias);
        *(float4*)(out + (size_t)b * 1024 + n4 * 16 + q4 * 4) = r;
    }
}

extern "C" void kernel_launch(void* const* d_in, const int* in_sizes, int n_in,
                              void* d_out, int out_size, void* d_ws, size_t ws_size,
                              hipStream_t stream) {
    const float* x    = (const float*)d_in[0];   // [B, In, Din]
    const float* W    = (const float*)d_in[1];   // [N, C, Dout, Din]
    const float* bias = (const float*)d_in[2];   // [N, Dout]
    float* out = (float*)d_out;                  // [B, N, Dout]

    float* ws     = (float*)d_ws;
    float* spart1 = ws;                                   // 32*8*64*16 = 262,144 f
    float* spart2 = spart1 + (size_t)B_ * 8 * N_ * Dout_; // 262,144 f
    float* v0buf  = spart2 + (size_t)B_ * 8 * N_ * Dout_; // 32,768 f
    unsigned* bar = (unsigned*)(v0buf + (size_t)B_ * N_ * Dout_); // 32 b x 32 u32

    // Zero the 4KB barrier state (workspace is poisoned between iterations).
    hipMemsetAsync(bar, 0, 32 * 32 * sizeof(unsigned), stream);

    caps_persist<<<GRID, 256, 0, stream>>>(x, W, bias, out, spart1, spart2,
                                           v0buf, bar);
}